// Round 2
// baseline (395.894 us; speedup 1.0000x reference)
//
#include <hip/hip_runtime.h>
#include <hip/hip_bf16.h>
#include <hip/hip_cooperative_groups.h>

namespace cg = cooperative_groups;

// Data_augV4: out[b] = t1(t0(x[b])), t from samples[(step, b)], 8 transforms.
// prob (d_in[1]) is dead code in the reference.
//
// Single cooperative kernel, 3 phases separated by grid.sync():
//  P1 : per-image sum0 = sum(x) (if any contrast involved) fused with
//       sum1 = sum(P0(x)) for t0 in {3,5,7} (pointwise, mean-free).
//       t0==6 (invert) is analytic: m1 = 1 - m0.  t0 in {0,1,2}: m1 = m0.
//  P1.5: sum1 for the rare t0==4 && t1==4 images (needs m0 first).
//  P2 : fused apply — net flips composed into the read address (flips
//       commute with pointwise ops; contrast mean is flip-invariant),
//       then P1(P0(v)) pointwise, coalesced float4 write.

#define B_    128
#define C_    3
#define H_    224
#define W_    224
#define N_ELEM (C_*H_*W_)        // 150528 per image
#define N4    (N_ELEM/4)         // 37632 float4 per image
#define W4    (W_/4)             // 56 float4 per row
#define HW4   (H_*W4)            // 12544 float4 per channel
#define S_    8                  // blocks per image
#define CHUNK (N4/S_)            // 4704 float4 per block

__device__ __forceinline__ float apply_pw(float v, int tf, float mean) {
    switch (tf) {
        case 3: return fminf(fmaxf(v * 1.5f, 0.0f), 1.0f);                  // brightness
        case 4: return fminf(fmaxf((v - mean) * 1.5f + mean, 0.0f), 1.0f);  // contrast
        case 5: return (v < 0.5f) ? v : (1.0f - v);                         // solarize
        case 6: return 1.0f - v;                                            // invert
        case 7: return floorf(v * 4.0f) * 0.25f;                            // posterize
        default: return v;   // identity / flips (handled via addressing)
    }
}

// Reduces two values across the block. Leading __syncthreads() protects the
// static smem against reuse across successive calls.
__device__ __forceinline__ float2 block_reduce_sum2(float a, float b) {
    #pragma unroll
    for (int o = 32; o > 0; o >>= 1) {
        a += __shfl_down(a, o, 64);
        b += __shfl_down(b, o, 64);
    }
    __shared__ float2 smem[4];
    const int lane = threadIdx.x & 63, wid = threadIdx.x >> 6;
    __syncthreads();
    if (lane == 0) smem[wid] = make_float2(a, b);
    __syncthreads();
    float2 r;
    r.x = ((smem[0].x + smem[1].x) + (smem[2].x + smem[3].x));
    r.y = ((smem[0].y + smem[1].y) + (smem[2].y + smem[3].y));
    return r;
}

__global__ __launch_bounds__(256, 4) void k_fused(const float* __restrict__ x,
                                                  const int* __restrict__ samples,
                                                  float* __restrict__ ws,
                                                  float* __restrict__ out) {
    cg::grid_group gg = cg::this_grid();
    const int img = blockIdx.x >> 3, blk = blockIdx.x & 7;
    const int t0 = samples[img], t1 = samples[B_ + img];
    float* partial0 = ws;                  // B_*S_ floats
    float* partial1 = ws + B_ * S_;        // B_*S_ floats
    const float4* xi = (const float4*)x + (size_t)img * N4;

    const bool need0  = (t0 == 4) || (t1 == 4);
    const bool need1e = (t1 == 4) && (t0 == 3 || t0 == 5 || t0 == 7);

    // ---- Phase 1: raw sum (+ easy P0 sum in the same read pass) ----
    if (need0) {
        float a0 = 0.f, a1 = 0.f;
        for (int i = threadIdx.x; i < CHUNK; i += 256) {
            float4 v = xi[blk * CHUNK + i];
            a0 += (v.x + v.y) + (v.z + v.w);
            if (need1e) {
                a1 += apply_pw(v.x, t0, 0.f) + apply_pw(v.y, t0, 0.f)
                    + apply_pw(v.z, t0, 0.f) + apply_pw(v.w, t0, 0.f);
            }
        }
        float2 r = block_reduce_sum2(a0, a1);
        if (threadIdx.x == 0) {
            partial0[img * S_ + blk] = r.x;
            if (need1e) partial1[img * S_ + blk] = r.y;
        }
    }
    gg.sync();

    // ---- Phase 1.5: sum(P0(x)) for double-contrast images only ----
    if (t0 == 4 && t1 == 4) {
        float s = 0.f;
        #pragma unroll
        for (int i = 0; i < S_; ++i) s += partial0[img * S_ + i];
        const float m0c = s * (1.0f / N_ELEM);
        float a1 = 0.f;
        for (int i = threadIdx.x; i < CHUNK; i += 256) {
            float4 v = xi[blk * CHUNK + i];
            a1 += apply_pw(v.x, 4, m0c) + apply_pw(v.y, 4, m0c)
                + apply_pw(v.z, 4, m0c) + apply_pw(v.w, 4, m0c);
        }
        float2 r = block_reduce_sum2(a1, 0.f);
        if (threadIdx.x == 0) partial1[img * S_ + blk] = r.x;
    }
    gg.sync();

    // ---- Phase 2: fused apply ----
    __shared__ float means[2];
    if (threadIdx.x == 0) {
        float m0 = 0.f, m1 = 0.f;
        if (need0) {
            float s = 0.f;
            #pragma unroll
            for (int i = 0; i < S_; ++i) s += partial0[img * S_ + i];
            m0 = s * (1.0f / N_ELEM);
        }
        if (t1 == 4) {
            if (t0 < 3)       m1 = m0;          // P0 identity-valued
            else if (t0 == 6) m1 = 1.0f - m0;   // invert: analytic
            else {                               // t0 in {3,5,7,4}
                float s = 0.f;
                #pragma unroll
                for (int i = 0; i < S_; ++i) s += partial1[img * S_ + i];
                m1 = s * (1.0f / N_ELEM);
            }
        }
        means[0] = m0; means[1] = m1;
    }
    __syncthreads();
    const float m0 = means[0], m1 = means[1];

    const bool fw = (t0 == 1) ^ (t1 == 1);       // net flip along W
    const bool fh = (t0 == 2) ^ (t1 == 2);       // net flip along H

    float4* oi = (float4*)out + (size_t)img * N4;
    for (int i = threadIdx.x; i < CHUNK; i += 256) {
        const int idx = blk * CHUNK + i;
        const int c = idx / HW4, rem = idx % HW4;
        const int h = rem / W4, wq = rem % W4;
        const int hs  = fh ? (H_ - 1 - h)  : h;
        const int wqs = fw ? (W4 - 1 - wq) : wq;
        float4 v = xi[c * HW4 + hs * W4 + wqs];
        if (fw) { float t = v.x; v.x = v.w; v.w = t; t = v.y; v.y = v.z; v.z = t; }
        v.x = apply_pw(apply_pw(v.x, t0, m0), t1, m1);
        v.y = apply_pw(apply_pw(v.y, t0, m0), t1, m1);
        v.z = apply_pw(apply_pw(v.z, t0, m0), t1, m1);
        v.w = apply_pw(apply_pw(v.w, t0, m0), t1, m1);
        oi[idx] = v;
    }
}

extern "C" void kernel_launch(void* const* d_in, const int* in_sizes, int n_in,
                              void* d_out, int out_size, void* d_ws, size_t ws_size,
                              hipStream_t stream) {
    const float* x       = (const float*)d_in[0];
    // d_in[1] (prob) is dead code in the reference.
    const int*   samples = (const int*)d_in[2];
    float*       out     = (float*)d_out;
    float*       ws      = (float*)d_ws;         // 2 * B_*S_ floats = 8 KB

    void* args[] = { (void*)&x, (void*)&samples, (void*)&ws, (void*)&out };
    hipLaunchCooperativeKernel((const void*)k_fused, dim3(B_ * S_), dim3(256),
                               args, 0, stream);
}

// Round 6
// 230.191 us; speedup vs baseline: 1.7198x; 1.7198x over previous
//
#include <hip/hip_runtime.h>
#include <hip/hip_bf16.h>

// Data_augV4: out[b] = t1(t0(x[b])), t from samples[(step, b)], 8 transforms.
// prob (d_in[1]) is dead code in the reference.
//
// Two plain dispatches (cooperative single-dispatch regressed: 281us @ 5.6%
// HBM — grid.sync serialization). Harness re-poison/restore ≈ 115us of the
// timed window is fixed; our budget is the ~40us of kernel work.
//
//  k_reduce: per-image sum0 = sum(x) partials (only if contrast involved),
//            fused in the SAME read pass with sum1 = sum(P0(x)) partials for
//            t0 in {3,5,7}. For the rare t0==4&&t1==4 (~2 of 128 images) one
//            block does both passes sequentially (2nd pass L2-hot).
//            t0 in {0,1,2}: mean1 = mean0 (flips preserve mean).
//            t0==6: mean1 = 1 - mean0 (analytic).
//  k_apply : net flips composed into the read address (flips commute with
//            pointwise ops; contrast mean is flip-invariant), pointwise chain
//            P1(P0(v)), nontemporal float4 stores.

#define B_    128
#define C_    3
#define H_    224
#define W_    224
#define N_ELEM (C_*H_*W_)        // 150528 per image
#define N4    (N_ELEM/4)         // 37632 float4 per image
#define W4    (W_/4)             // 56 float4 per row
#define HW4   (H_*W4)            // 12544 float4 per channel
#define S_    8                  // reduce blocks per image
#define CHUNK (N4/S_)            // 4704 float4 per reduce block
#define ABPI  21                 // apply blocks per image (21*256*7 == 37632)
#define APT   7                  // float4 per thread in apply

typedef float f32x4 __attribute__((ext_vector_type(4)));

__device__ __forceinline__ float apply_pw(float v, int tf, float mean) {
    switch (tf) {
        case 3: return fminf(fmaxf(v * 1.5f, 0.0f), 1.0f);                  // brightness
        case 4: return fminf(fmaxf((v - mean) * 1.5f + mean, 0.0f), 1.0f);  // contrast
        case 5: return (v < 0.5f) ? v : (1.0f - v);                         // solarize
        case 6: return 1.0f - v;                                            // invert
        case 7: return floorf(v * 4.0f) * 0.25f;                            // posterize
        default: return v;   // identity / flips (handled via addressing)
    }
}

// Two-value block reduction; safe to call repeatedly (leading sync).
__device__ __forceinline__ float2 block_reduce_sum2(float a, float b) {
    #pragma unroll
    for (int o = 32; o > 0; o >>= 1) {
        a += __shfl_down(a, o, 64);
        b += __shfl_down(b, o, 64);
    }
    __shared__ float2 smem[4];
    const int lane = threadIdx.x & 63, wid = threadIdx.x >> 6;
    __syncthreads();
    if (lane == 0) smem[wid] = make_float2(a, b);
    __syncthreads();
    float2 r;
    r.x = (smem[0].x + smem[1].x) + (smem[2].x + smem[3].x);
    r.y = (smem[0].y + smem[1].y) + (smem[2].y + smem[3].y);
    return r;
}

__global__ __launch_bounds__(256) void k_reduce(const float* __restrict__ x,
                                                const int* __restrict__ samples,
                                                float* __restrict__ ws) {
    const int img = blockIdx.x >> 3, blk = blockIdx.x & 7;
    const int t0 = samples[img], t1 = samples[B_ + img];
    float* p0 = ws;                  // B_*S_ floats
    float* p1 = ws + B_ * S_;        // B_*S_ floats
    const float4* xi = (const float4*)x + (size_t)img * N4;

    if (t0 == 4 && t1 == 4) {        // double contrast: one block, two passes
        if (blk != 0) return;
        float a = 0.f;
        for (int i = threadIdx.x; i < N4; i += 256) {
            float4 v = xi[i];
            a += (v.x + v.y) + (v.z + v.w);
        }
        float2 r0 = block_reduce_sum2(a, 0.f);
        const float m0 = r0.x * (1.0f / N_ELEM);
        float b = 0.f;
        for (int i = threadIdx.x; i < N4; i += 256) {   // L2-hot re-read
            float4 v = xi[i];
            b += apply_pw(v.x, 4, m0) + apply_pw(v.y, 4, m0)
               + apply_pw(v.z, 4, m0) + apply_pw(v.w, 4, m0);
        }
        float2 r1 = block_reduce_sum2(b, 0.f);
        if (threadIdx.x < S_) {      // fill all slots (ws is poisoned)
            p0[img * S_ + threadIdx.x] = (threadIdx.x == 0) ? r0.x : 0.f;
            p1[img * S_ + threadIdx.x] = (threadIdx.x == 0) ? r1.x : 0.f;
        }
        return;
    }

    const bool need0 = (t0 == 4) || (t1 == 4);
    if (!need0) return;
    const bool need1 = (t1 == 4) && (t0 == 3 || t0 == 5 || t0 == 7);

    const float4* xc = xi + blk * CHUNK;
    float a0 = 0.f, a1 = 0.f;
    for (int i = threadIdx.x; i < CHUNK; i += 256) {
        float4 v = xc[i];
        a0 += (v.x + v.y) + (v.z + v.w);
        if (need1) {
            a1 += apply_pw(v.x, t0, 0.f) + apply_pw(v.y, t0, 0.f)
                + apply_pw(v.z, t0, 0.f) + apply_pw(v.w, t0, 0.f);
        }
    }
    float2 r = block_reduce_sum2(a0, a1);
    if (threadIdx.x == 0) {
        p0[img * S_ + blk] = r.x;
        if (need1) p1[img * S_ + blk] = r.y;
    }
}

__global__ __launch_bounds__(256) void k_apply(const float* __restrict__ x,
                                               const int* __restrict__ samples,
                                               const float* __restrict__ ws,
                                               float* __restrict__ out) {
    const int img = blockIdx.x / ABPI;
    const int t0 = samples[img], t1 = samples[B_ + img];
    const float* p0 = ws;
    const float* p1 = ws + B_ * S_;

    __shared__ float means[2];
    if (threadIdx.x == 0) {
        float m0 = 0.f, m1 = 0.f;
        if (t0 == 4 || t1 == 4) {
            float s = 0.f;
            #pragma unroll
            for (int i = 0; i < S_; ++i) s += p0[img * S_ + i];
            m0 = s * (1.0f / N_ELEM);
        }
        if (t1 == 4) {
            if (t0 < 3)       m1 = m0;          // flips/identity preserve mean
            else if (t0 == 6) m1 = 1.0f - m0;   // invert: analytic
            else {                              // t0 in {3,4,5,7}
                float s = 0.f;
                #pragma unroll
                for (int i = 0; i < S_; ++i) s += p1[img * S_ + i];
                m1 = s * (1.0f / N_ELEM);
            }
        }
        means[0] = m0; means[1] = m1;
    }
    __syncthreads();
    const float m0 = means[0], m1 = means[1];

    const bool fw = (t0 == 1) ^ (t1 == 1);      // net flip along W
    const bool fh = (t0 == 2) ^ (t1 == 2);      // net flip along H

    const float4* xi = (const float4*)x + (size_t)img * N4;
    f32x4* oi = (f32x4*)out + (size_t)img * N4;
    const int base = (blockIdx.x % ABPI) * (256 * APT) + threadIdx.x;

    #pragma unroll
    for (int k = 0; k < APT; ++k) {
        const int idx = base + k * 256;         // < N4 by construction
        const int c = idx / HW4, rem = idx % HW4;
        const int h = rem / W4, wq = rem % W4;
        const int hs  = fh ? (H_ - 1 - h)  : h;
        const int wqs = fw ? (W4 - 1 - wq) : wq;
        float4 v = xi[c * HW4 + hs * W4 + wqs];
        if (fw) { float t = v.x; v.x = v.w; v.w = t; t = v.y; v.y = v.z; v.z = t; }
        f32x4 r;
        r.x = apply_pw(apply_pw(v.x, t0, m0), t1, m1);
        r.y = apply_pw(apply_pw(v.y, t0, m0), t1, m1);
        r.z = apply_pw(apply_pw(v.z, t0, m0), t1, m1);
        r.w = apply_pw(apply_pw(v.w, t0, m0), t1, m1);
        __builtin_nontemporal_store(r, &oi[idx]);
    }
}

extern "C" void kernel_launch(void* const* d_in, const int* in_sizes, int n_in,
                              void* d_out, int out_size, void* d_ws, size_t ws_size,
                              hipStream_t stream) {
    const float* x       = (const float*)d_in[0];
    // d_in[1] (prob) is dead code in the reference.
    const int*   samples = (const int*)d_in[2];
    float*       out     = (float*)d_out;
    float*       ws      = (float*)d_ws;        // 2 * B_*S_ floats = 8 KB

    k_reduce<<<B_ * S_,   256, 0, stream>>>(x, samples, ws);
    k_apply <<<B_ * ABPI, 256, 0, stream>>>(x, samples, ws, out);
}

// Round 7
// 151.110 us; speedup vs baseline: 2.6199x; 1.5233x over previous
//
#include <hip/hip_runtime.h>
#include <hip/hip_bf16.h>

// Data_augV4: out[b] = t1(t0(x[b])), t from samples[(step, b)], 8 transforms.
// prob (d_in[1]) is dead code in the reference.
//
// Round-6 post-mortem: single-block double-contrast path was a 93us serial
// tail (1 block, 2 dependent full-image passes, 1.4% HBM). Fix: 3 dispatches,
// every data pass spread over 32 blocks/image (parallelism beats launch cost).
//
//  k_reduce : per-image sum0 = sum(x) partials (32 blocks/img, only if a
//             contrast is involved), fused in the SAME read pass with
//             sum1 = sum(P0(x)) partials for t0 in {3,5,7} (mean-free).
//  k_reduce2: sum1 partials for the rare t0==4 && t1==4 images only
//             (~1/64 of images); needs m0 from k_reduce. Early-exit else.
//             t0 in {0,1,2}: mean1 = mean0 (flips preserve mean).
//             t0 == 6     : mean1 = 1 - mean0 (analytic).
//  k_apply  : net flips composed into the read address (flips commute with
//             pointwise ops; contrast mean is flip-invariant), pointwise
//             chain P1(P0(v)), nontemporal float4 stores.

#define B_    128
#define C_    3
#define H_    224
#define W_    224
#define N_ELEM (C_*H_*W_)        // 150528 per image
#define N4    (N_ELEM/4)         // 37632 float4 per image
#define W4    (W_/4)             // 56 float4 per row
#define HW4   (H_*W4)            // 12544 float4 per channel
#define S_    32                 // reduce blocks per image
#define CHUNK (N4/S_)            // 1176 float4 per reduce block
#define ABPI  21                 // apply blocks per image (21*256*7 == 37632)
#define APT   7                  // float4 per thread in apply

typedef float f32x4 __attribute__((ext_vector_type(4)));

__device__ __forceinline__ float apply_pw(float v, int tf, float mean) {
    switch (tf) {
        case 3: return fminf(fmaxf(v * 1.5f, 0.0f), 1.0f);                  // brightness
        case 4: return fminf(fmaxf((v - mean) * 1.5f + mean, 0.0f), 1.0f);  // contrast
        case 5: return (v < 0.5f) ? v : (1.0f - v);                         // solarize
        case 6: return 1.0f - v;                                            // invert
        case 7: return floorf(v * 4.0f) * 0.25f;                            // posterize
        default: return v;   // identity / flips (handled via addressing)
    }
}

// Two-value block reduction; safe to call repeatedly (leading sync).
__device__ __forceinline__ float2 block_reduce_sum2(float a, float b) {
    #pragma unroll
    for (int o = 32; o > 0; o >>= 1) {
        a += __shfl_down(a, o, 64);
        b += __shfl_down(b, o, 64);
    }
    __shared__ float2 smem[4];
    const int lane = threadIdx.x & 63, wid = threadIdx.x >> 6;
    __syncthreads();
    if (lane == 0) smem[wid] = make_float2(a, b);
    __syncthreads();
    float2 r;
    r.x = (smem[0].x + smem[1].x) + (smem[2].x + smem[3].x);
    r.y = (smem[0].y + smem[1].y) + (smem[2].y + smem[3].y);
    return r;
}

__global__ __launch_bounds__(256) void k_reduce(const float* __restrict__ x,
                                                const int* __restrict__ samples,
                                                float* __restrict__ ws) {
    const int img = blockIdx.x >> 5, blk = blockIdx.x & 31;
    const int t0 = samples[img], t1 = samples[B_ + img];
    if (!((t0 == 4) || (t1 == 4))) return;      // mean0 never consumed
    const bool need1 = (t1 == 4) && (t0 == 3 || t0 == 5 || t0 == 7);
    float* p0 = ws;                  // B_*S_ floats
    float* p1 = ws + B_ * S_;        // B_*S_ floats
    const float4* xc = (const float4*)x + (size_t)img * N4 + blk * CHUNK;

    float a0 = 0.f, a1 = 0.f;
    for (int i = threadIdx.x; i < CHUNK; i += 256) {
        float4 v = xc[i];
        a0 += (v.x + v.y) + (v.z + v.w);
        if (need1) {
            a1 += apply_pw(v.x, t0, 0.f) + apply_pw(v.y, t0, 0.f)
                + apply_pw(v.z, t0, 0.f) + apply_pw(v.w, t0, 0.f);
        }
    }
    float2 r = block_reduce_sum2(a0, a1);
    if (threadIdx.x == 0) {
        p0[img * S_ + blk] = r.x;
        if (need1) p1[img * S_ + blk] = r.y;
    }
}

// Second pass for double-contrast images only (expected ~2 of 128).
__global__ __launch_bounds__(256) void k_reduce2(const float* __restrict__ x,
                                                 const int* __restrict__ samples,
                                                 float* __restrict__ ws) {
    const int img = blockIdx.x >> 5, blk = blockIdx.x & 31;
    const int t0 = samples[img], t1 = samples[B_ + img];
    if (!(t0 == 4 && t1 == 4)) return;
    const float* p0 = ws;
    float* p1 = ws + B_ * S_;

    float s = 0.f;                               // wave-uniform scalar loads
    #pragma unroll
    for (int i = 0; i < S_; ++i) s += p0[img * S_ + i];
    const float m0 = s * (1.0f / N_ELEM);

    const float4* xc = (const float4*)x + (size_t)img * N4 + blk * CHUNK;
    float a1 = 0.f;
    for (int i = threadIdx.x; i < CHUNK; i += 256) {
        float4 v = xc[i];                        // L2/L3-hot re-read
        a1 += apply_pw(v.x, 4, m0) + apply_pw(v.y, 4, m0)
            + apply_pw(v.z, 4, m0) + apply_pw(v.w, 4, m0);
    }
    float2 r = block_reduce_sum2(a1, 0.f);
    if (threadIdx.x == 0) p1[img * S_ + blk] = r.x;
}

__global__ __launch_bounds__(256) void k_apply(const float* __restrict__ x,
                                               const int* __restrict__ samples,
                                               const float* __restrict__ ws,
                                               float* __restrict__ out) {
    const int img = blockIdx.x / ABPI;
    const int t0 = samples[img], t1 = samples[B_ + img];
    const float* p0 = ws;
    const float* p1 = ws + B_ * S_;

    __shared__ float means[2];
    if (threadIdx.x == 0) {
        float m0 = 0.f, m1 = 0.f;
        if (t0 == 4 || t1 == 4) {
            float s = 0.f;
            #pragma unroll
            for (int i = 0; i < S_; ++i) s += p0[img * S_ + i];
            m0 = s * (1.0f / N_ELEM);
        }
        if (t1 == 4) {
            if (t0 < 3)       m1 = m0;          // flips/identity preserve mean
            else if (t0 == 6) m1 = 1.0f - m0;   // invert: analytic
            else {                              // t0 in {3,4,5,7}
                float s = 0.f;
                #pragma unroll
                for (int i = 0; i < S_; ++i) s += p1[img * S_ + i];
                m1 = s * (1.0f / N_ELEM);
            }
        }
        means[0] = m0; means[1] = m1;
    }
    __syncthreads();
    const float m0 = means[0], m1 = means[1];

    const bool fw = (t0 == 1) ^ (t1 == 1);      // net flip along W
    const bool fh = (t0 == 2) ^ (t1 == 2);      // net flip along H

    const float4* xi = (const float4*)x + (size_t)img * N4;
    f32x4* oi = (f32x4*)out + (size_t)img * N4;
    const int base = (blockIdx.x % ABPI) * (256 * APT) + threadIdx.x;

    #pragma unroll
    for (int k = 0; k < APT; ++k) {
        const int idx = base + k * 256;         // < N4 by construction
        const int c = idx / HW4, rem = idx % HW4;
        const int h = rem / W4, wq = rem % W4;
        const int hs  = fh ? (H_ - 1 - h)  : h;
        const int wqs = fw ? (W4 - 1 - wq) : wq;
        float4 v = xi[c * HW4 + hs * W4 + wqs];
        if (fw) { float t = v.x; v.x = v.w; v.w = t; t = v.y; v.y = v.z; v.z = t; }
        f32x4 r;
        r.x = apply_pw(apply_pw(v.x, t0, m0), t1, m1);
        r.y = apply_pw(apply_pw(v.y, t0, m0), t1, m1);
        r.z = apply_pw(apply_pw(v.z, t0, m0), t1, m1);
        r.w = apply_pw(apply_pw(v.w, t0, m0), t1, m1);
        __builtin_nontemporal_store(r, &oi[idx]);
    }
}

extern "C" void kernel_launch(void* const* d_in, const int* in_sizes, int n_in,
                              void* d_out, int out_size, void* d_ws, size_t ws_size,
                              hipStream_t stream) {
    const float* x       = (const float*)d_in[0];
    // d_in[1] (prob) is dead code in the reference.
    const int*   samples = (const int*)d_in[2];
    float*       out     = (float*)d_out;
    float*       ws      = (float*)d_ws;        // 2 * B_*S_ floats = 32 KB

    k_reduce <<<B_ * S_,   256, 0, stream>>>(x, samples, ws);
    k_reduce2<<<B_ * S_,   256, 0, stream>>>(x, samples, ws);
    k_apply  <<<B_ * ABPI, 256, 0, stream>>>(x, samples, ws, out);
}